// Round 7
// baseline (135.366 us; speedup 1.0000x reference)
//
#include <hip/hip_runtime.h>
#include <math.h>

#define C_IN    256
#define C_HEAD  32
#define HW      361          // 19*19
#define NTHR    384          // 6 waves
#define CV      48
#define WSTR    264          // wtT row stride (bf16 elems): 528B rows, 16B-aligned cols
#define CCHUNK  32           // channels per chunk
#define NCHUNK  8
#define QUADS   2888         // 361*32/4 — chunk slab is quad-exact
#define PSTRIDE 40           // x-tile row stride in bf16 elems (80B): bank-balanced, 16B-aligned
#define XBUF    (364 * PSTRIDE)

typedef __attribute__((ext_vector_type(8))) short bf16x8;
typedef __attribute__((ext_vector_type(4))) float f32x4;

static __device__ __forceinline__ unsigned short f2bf(float f) {
    unsigned int u = __builtin_bit_cast(unsigned int, f);
    u += 0x7fffu + ((u >> 16) & 1u);          // RNE
    return (unsigned short)(u >> 16);
}

__global__ __launch_bounds__(NTHR, 3) void vh_fused(
    const float* __restrict__ x,
    const float* __restrict__ conv_w,
    const float* __restrict__ fc1_w, const float* __restrict__ fc1_b,
    const float* __restrict__ fc2_w, const float* __restrict__ fc2_b,
    const float* __restrict__ fc3_w, const float* __restrict__ fc3_b,
    const float* __restrict__ sc_w,  const float* __restrict__ sc_b,
    const float* __restrict__ fc4_w, const float* __restrict__ fc4_b,
    const float* __restrict__ fc5_w, const float* __restrict__ fc5_b,
    float* __restrict__ out, int B)
{
    const int b    = blockIdx.x;
    const int tid  = threadIdx.x;
    const int wave = tid >> 6;
    const int lane = tid & 63;
    const int l15  = lane & 15;
    const int g    = lane >> 4;

    __shared__ __align__(16) unsigned short wtT[C_HEAD * WSTR];  // 16.9 KB
    __shared__ __align__(16) unsigned short xs[2][XBUF];         // 2 x 29.1 KB
    __shared__ float lds_psum[C_HEAD][6];
    __shared__ float lds_pmax[C_HEAD][6];
    __shared__ float vp[3 * C_HEAD];
    __shared__ float base_l[CV], dco_l[CV], f5_l[CV];

    // ---- one-time: W as bf16 into LDS, [o][c] (k-contiguous for B-frag) ----
    for (int i = tid; i < C_HEAD * C_IN; i += NTHR) {
        int o = i >> 8, c = i & 255;
        wtT[o * WSTR + c] = f2bf(conv_w[i]);
    }

    f32x4 acc[4][2];
    #pragma unroll
    for (int mi = 0; mi < 4; ++mi)
        #pragma unroll
        for (int n = 0; n < 2; ++n)
            acc[mi][n] = (f32x4){0.f, 0.f, 0.f, 0.f};

    const float* __restrict__ xb = x + (size_t)b * (C_IN * HW);

    // A-fragment rows (clamped; tail masked at reduction)
    int prow[4];
    #pragma unroll
    for (int mi = 0; mi < 4; ++mi) {
        int p = wave * 64 + mi * 16 + l15;
        prow[mi] = (p < HW) ? p : (HW - 1);
    }

    float4 vreg[8];

    // dense aligned float4 loads over the chunk's flat [32c x 361p] slab
    auto issue = [&](int q) {
        const float4* src = (const float4*)(xb + q * (CCHUNK * HW));
        #pragma unroll
        for (int s = 0; s < 8; ++s) {
            int it = s * NTHR + tid;
            if (it < QUADS) vreg[s] = src[it];
        }
    };

    // convert + transpose-scatter into xs[buf][p][c_local]
    auto convwrite = [&](int buf) {
        #pragma unroll
        for (int s = 0; s < 8; ++s) {
            int it = s * NTHR + tid;
            if (it < QUADS) {
                int f = it * 4;
                int c = (int)__umulhi((unsigned)f, 11897417u);   // f / 361
                int p0 = f - c * 361;
                float vv[4] = {vreg[s].x, vreg[s].y, vreg[s].z, vreg[s].w};
                #pragma unroll
                for (int i = 0; i < 4; ++i) {
                    int p = p0 + i, cc = c;
                    if (p >= HW) { p -= HW; ++cc; }   // row-crossing quad
                    xs[buf][p * PSTRIDE + cc] = f2bf(vv[i]);
                }
            }
        }
    };

    // prologue: stage chunk 0 (barrier at loop top publishes it)
    issue(0);
    convwrite(0);

    // ---- main loop: 1 barrier/chunk; t+1 loads in flight across compute+write ----
    #pragma unroll
    for (int t = 0; t < NCHUNK; ++t) {
        __syncthreads();                       // xs[t&1] (and wtT on t==0) ready
        if (t < NCHUNK - 1) issue(t + 1);

        bf16x8 wf0 = *(const bf16x8*)&wtT[(     l15) * WSTR + t * 32 + g * 8];
        bf16x8 wf1 = *(const bf16x8*)&wtT[(16 + l15) * WSTR + t * 32 + g * 8];

        const unsigned short* xc = xs[t & 1];
        #pragma unroll
        for (int mi = 0; mi < 4; ++mi) {
            bf16x8 a = *(const bf16x8*)&xc[prow[mi] * PSTRIDE + g * 8];
            acc[mi][0] = __builtin_amdgcn_mfma_f32_16x16x32_bf16(a, wf0, acc[mi][0], 0, 0, 0);
            acc[mi][1] = __builtin_amdgcn_mfma_f32_16x16x32_bf16(a, wf1, acc[mi][1], 0, 0, 0);
        }

        if (t < NCHUNK - 1) convwrite((t + 1) & 1);
    }

    // ---- reduce over positions: lane holds D[p = wave*64+mi*16+g*4+r][o = n*16+l15] ----
    float s[2]  = {0.f, 0.f};
    float mx[2] = {-3.0e38f, -3.0e38f};
    #pragma unroll
    for (int n = 0; n < 2; ++n) {
        #pragma unroll
        for (int mi = 0; mi < 4; ++mi) {
            #pragma unroll
            for (int r = 0; r < 4; ++r) {
                int pp = wave * 64 + mi * 16 + g * 4 + r;
                float v = acc[mi][n][r];
                if (pp < HW) { s[n] += v; mx[n] = fmaxf(mx[n], v); }
            }
        }
        s[n] += __shfl_xor(s[n], 16, 64);
        s[n] += __shfl_xor(s[n], 32, 64);
        mx[n] = fmaxf(mx[n], __shfl_xor(mx[n], 16, 64));
        mx[n] = fmaxf(mx[n], __shfl_xor(mx[n], 32, 64));
    }
    if (lane < 32) {
        lds_psum[lane][wave] = (lane < 16) ? s[0] : s[1];
        lds_pmax[lane][wave] = (lane < 16) ? mx[0] : mx[1];
    }
    __syncthreads();

    if (tid < C_HEAD) {
        float ss = 0.f, mm = -3.0e38f;
        #pragma unroll
        for (int w = 0; w < 6; ++w) { ss += lds_psum[tid][w]; mm = fmaxf(mm, lds_pmax[tid][w]); }
        float mean1 = ss * (1.0f / (float)HW);
        vp[tid]              = mean1;
        vp[C_HEAD + tid]     = mean1 * ((19.0f - 9.0f) * 0.1f);
        vp[2 * C_HEAD + tid] = mm;
    }
    __syncthreads();

    // ---- heads: wave 0 ----
    if (wave == 0) {
        const int j = lane;
        float h1 = 0.f, h3 = 0.f;
        if (j < CV) {
            float a1 = fc1_b[j], a3 = fc3_b[j], a4 = fc4_b[j];
            #pragma unroll
            for (int k = 0; k < 96; ++k) {
                float v = vp[k];
                a1 = fmaf(v, fc1_w[j * 96 + k], a1);
                a3 = fmaf(v, fc3_w[j * 96 + k], a3);
                a4 = fmaf(v, fc4_w[j * 97 + k], a4);
            }
            h1 = fmaxf(a1, 0.f) * fc2_w[j];
            h3 = fmaxf(a3, 0.f) * sc_w[j];
            base_l[j] = a4;
            dco_l[j]  = fc4_w[j * 97 + 96];
            f5_l[j]   = fc5_w[j];
        }
        float s1 = h1, s3 = h3;
        #pragma unroll
        for (int off = 32; off > 0; off >>= 1) {
            s1 += __shfl_xor(s1, off, 64);
            s3 += __shfl_xor(s3, off, 64);
        }
        float game = tanhf(s1 + fc2_b[0]);
        float scal = s3 + sc_b[0];
        if (lane == 0) out[b] = game;

        float z = -3.0e38f;
        if (lane < 41) {
            float dval = (float)(lane - 20);
            float lg = fc5_b[0];
            #pragma unroll
            for (int jj = 0; jj < CV; ++jj) {
                float t2 = fmaf(dval, dco_l[jj], base_l[jj]);
                t2 = fmaxf(t2, 0.f);
                lg = fmaf(t2, f5_l[jj], lg);
            }
            z = lg * scal;
        }
        float mz = z;
        #pragma unroll
        for (int off = 32; off > 0; off >>= 1) mz = fmaxf(mz, __shfl_xor(mz, off, 64));
        float e = (lane < 41) ? expf(z - mz) : 0.f;
        float se = e;
        #pragma unroll
        for (int off = 32; off > 0; off >>= 1) se += __shfl_xor(se, off, 64);
        if (lane < 41) out[B + b * 41 + lane] = e / se;
    }
}

extern "C" void kernel_launch(void* const* d_in, const int* in_sizes, int n_in,
                              void* d_out, int out_size, void* d_ws, size_t ws_size,
                              hipStream_t stream) {
    const float* x      = (const float*)d_in[0];
    const float* conv_w = (const float*)d_in[1];
    const float* fc1_w  = (const float*)d_in[2];
    const float* fc1_b  = (const float*)d_in[3];
    const float* fc2_w  = (const float*)d_in[4];
    const float* fc2_b  = (const float*)d_in[5];
    const float* fc3_w  = (const float*)d_in[6];
    const float* fc3_b  = (const float*)d_in[7];
    const float* sc_w   = (const float*)d_in[8];
    const float* sc_b   = (const float*)d_in[9];
    const float* fc4_w  = (const float*)d_in[10];
    const float* fc4_b  = (const float*)d_in[11];
    const float* fc5_w  = (const float*)d_in[12];
    const float* fc5_b  = (const float*)d_in[13];
    float* out = (float*)d_out;

    int B = in_sizes[0] / (C_IN * HW);

    vh_fused<<<dim3(B), dim3(NTHR), 0, stream>>>(
        x, conv_w, fc1_w, fc1_b, fc2_w, fc2_b, fc3_w, fc3_b,
        sc_w, sc_b, fc4_w, fc4_b, fc5_w, fc5_b, out, B);
}

// Round 9
// 91.890 us; speedup vs baseline: 1.4731x; 1.4731x over previous
//
#include <hip/hip_runtime.h>
#include <math.h>

#define C_IN   256
#define C_HEAD 32
#define HW     361          // 19*19
#define NTHR   384          // 6 waves
#define CV     48
#define WSTR   264          // wtT row stride (bf16 elems)
#define NCHUNK 8
#define FLIM   (C_IN * HW - 4)   // 92412: last aligned quad start
// wave-private x staging: row (wave,g,e) = 68 floats; slot j holds q = j - (e&3)
#define GSTR   552          // 8 rows * 68 + 8 skew
#define WVSTR  2208         // 4 * GSTR
#define XSF    (6 * WVSTR)  // 13248 floats = 53 KB

typedef __attribute__((ext_vector_type(8))) short bf16x8;
typedef __attribute__((ext_vector_type(4))) float f32x4;

static __device__ __forceinline__ unsigned short f2bf(float f) {
    unsigned int u = __builtin_bit_cast(unsigned int, f);
    u += 0x7fffu + ((u >> 16) & 1u);          // RNE (one-time weight prep only)
    return (unsigned short)(u >> 16);
}

__global__ __launch_bounds__(NTHR, 3) void vh_fused(
    const float* __restrict__ x,
    const float* __restrict__ conv_w,
    const float* __restrict__ fc1_w, const float* __restrict__ fc1_b,
    const float* __restrict__ fc2_w, const float* __restrict__ fc2_b,
    const float* __restrict__ fc3_w, const float* __restrict__ fc3_b,
    const float* __restrict__ sc_w,  const float* __restrict__ sc_b,
    const float* __restrict__ fc4_w, const float* __restrict__ fc4_b,
    const float* __restrict__ fc5_w, const float* __restrict__ fc5_b,
    float* __restrict__ out, int B)
{
    const int b    = blockIdx.x;
    const int tid  = threadIdx.x;
    const int wave = tid >> 6;
    const int lane = tid & 63;
    const int l15  = lane & 15;
    const int g    = lane >> 4;

    __shared__ __align__(16) unsigned short wtT[C_HEAD * WSTR];  // 16.9 KB
    __shared__ __align__(16) float xs[XSF];                      // 53 KB wave-private staging
    __shared__ float lds_psum[C_HEAD][6];
    __shared__ float lds_pmax[C_HEAD][6];
    __shared__ float vp[3 * C_HEAD];
    __shared__ float base_l[CV], dco_l[CV], f5_l[CV];

    // ---- one-time: W as bf16 into LDS, [o][c] (k-contiguous for B-frag) ----
    for (int i = tid; i < C_HEAD * C_IN; i += NTHR) {
        int o = i >> 8, c = i & 255;
        wtT[o * WSTR + c] = f2bf(conv_w[i]);
    }
    __syncthreads();   // the only block-wide barrier before the reduction

    f32x4 acc[4][2];
    #pragma unroll
    for (int mi = 0; mi < 4; ++mi)
        #pragma unroll
        for (int n = 0; n < 2; ++n)
            acc[mi][n] = (f32x4){0.f, 0.f, 0.f, 0.f};

    const float* __restrict__ xb = x + (size_t)b * (C_IN * HW);

    // thread-invariant pieces
    const int thbase = g * (8 * HW) + wave * 64 + l15 * 4;   // flat elem base for loads
    const int wb_w   = wave * WVSTR + g * GSTR + l15 * 4;    // LDS write base (floats)
    const int wb_r   = wave * WVSTR + g * GSTR + l15;        // LDS read base  (floats)
    const int ep     = l15 & 7;                               // tail row this lane serves

    float4 va[9], vb[9];

    // issue 9 aligned dwordx4 loads for chunk t (8 main quads + 1 tail quad)
    auto issue = [&](int t, float4 (&bank)[9]) {
        #pragma unroll
        for (int e = 0; e < 8; ++e) {
            int F = thbase + ((t * 32 + e) * HW - (e & 3));
            if (t == NCHUNK - 1 && e == 7)
                F = (F > FLIM) ? FLIM : F;                    // c=255 buffer-end clamp
            bank[e] = *(const float4*)(xb + F);
        }
        // tail quad for row (g, ep): slots 64..67 = q in [64-s, 67-s]
        int Ft = (t * 32 + g * 8 + ep) * HW + wave * 64 + 64 - (ep & 3);
        if (t == NCHUNK - 1) Ft = (Ft > FLIM) ? FLIM : Ft;    // clamped vals land at q>=61 of wave5: masked
        bank[8] = *(const float4*)(xb + Ft);
    };

    // publish chunk's bank to wave-private LDS
    auto write_lds = [&](float4 (&bank)[9]) {
        #pragma unroll
        for (int e = 0; e < 8; ++e)
            *(float4*)&xs[wb_w + e * 68] = bank[e];           // slots l15*4..+3
        if (l15 < 8)
            *(float4*)&xs[wave * WVSTR + g * GSTR + ep * 68 + 64] = bank[8];  // slots 64..67
    };

    // consume chunk t from LDS: convert + 8 MFMAs
    auto compute = [&](int t) {
        bf16x8 wf0 = *(const bf16x8*)&wtT[(     l15) * WSTR + t * 32 + g * 8];
        bf16x8 wf1 = *(const bf16x8*)&wtT[(16 + l15) * WSTR + t * 32 + g * 8];
        #pragma unroll
        for (int mi = 0; mi < 4; ++mi) {
            float af[8];
            #pragma unroll
            for (int e = 0; e < 8; ++e)
                af[e] = xs[wb_r + e * 68 + mi * 16 + (e & 3)];   // q = mi*16 + l15
            unsigned u0, u1, u2, u3;
            asm("v_cvt_pk_bf16_f32 %0, %1, %2" : "=v"(u0) : "v"(af[0]), "v"(af[1]));
            asm("v_cvt_pk_bf16_f32 %0, %1, %2" : "=v"(u1) : "v"(af[2]), "v"(af[3]));
            asm("v_cvt_pk_bf16_f32 %0, %1, %2" : "=v"(u2) : "v"(af[4]), "v"(af[5]));
            asm("v_cvt_pk_bf16_f32 %0, %1, %2" : "=v"(u3) : "v"(af[6]), "v"(af[7]));
            uint4 up = make_uint4(u0, u1, u2, u3);
            bf16x8 a = __builtin_bit_cast(bf16x8, up);
            acc[mi][0] = __builtin_amdgcn_mfma_f32_16x16x32_bf16(a, wf0, acc[mi][0], 0, 0, 0);
            acc[mi][1] = __builtin_amdgcn_mfma_f32_16x16x32_bf16(a, wf1, acc[mi][1], 0, 0, 0);
        }
    };

    // ---- main loop: no barriers; loads 2 chunks ahead in alternating banks ----
    issue(0, va);
    issue(1, vb);
    #pragma unroll
    for (int t = 0; t < NCHUNK; ++t) {
        if ((t & 1) == 0) {
            write_lds(va);
            if (t + 2 < NCHUNK) issue(t + 2, va);
        } else {
            write_lds(vb);
            if (t + 2 < NCHUNK) issue(t + 2, vb);
        }
        compute(t);
    }

    // ---- reduce over positions: lane holds D[p = wave*64+mi*16+g*4+r][o = n*16+l15] ----
    float s[2]  = {0.f, 0.f};
    float mx[2] = {-3.0e38f, -3.0e38f};
    #pragma unroll
    for (int n = 0; n < 2; ++n) {
        #pragma unroll
        for (int mi = 0; mi < 4; ++mi) {
            #pragma unroll
            for (int r = 0; r < 4; ++r) {
                int pp = wave * 64 + mi * 16 + g * 4 + r;
                float v = acc[mi][n][r];
                if (pp < HW) { s[n] += v; mx[n] = fmaxf(mx[n], v); }
            }
        }
        s[n] += __shfl_xor(s[n], 16, 64);
        s[n] += __shfl_xor(s[n], 32, 64);
        mx[n] = fmaxf(mx[n], __shfl_xor(mx[n], 16, 64));
        mx[n] = fmaxf(mx[n], __shfl_xor(mx[n], 32, 64));
    }
    if (lane < 32) {
        lds_psum[lane][wave] = (lane < 16) ? s[0] : s[1];
        lds_pmax[lane][wave] = (lane < 16) ? mx[0] : mx[1];
    }
    __syncthreads();

    if (tid < C_HEAD) {
        float ss = 0.f, mm = -3.0e38f;
        #pragma unroll
        for (int w = 0; w < 6; ++w) { ss += lds_psum[tid][w]; mm = fmaxf(mm, lds_pmax[tid][w]); }
        float mean1 = ss * (1.0f / (float)HW);
        vp[tid]              = mean1;
        vp[C_HEAD + tid]     = mean1 * ((19.0f - 9.0f) * 0.1f);
        vp[2 * C_HEAD + tid] = mm;
    }
    __syncthreads();

    // ---- heads: wave 0 ----
    if (wave == 0) {
        const int j = lane;
        float h1 = 0.f, h3 = 0.f;
        if (j < CV) {
            float a1 = fc1_b[j], a3 = fc3_b[j], a4 = fc4_b[j];
            #pragma unroll
            for (int k = 0; k < 96; ++k) {
                float v = vp[k];
                a1 = fmaf(v, fc1_w[j * 96 + k], a1);
                a3 = fmaf(v, fc3_w[j * 96 + k], a3);
                a4 = fmaf(v, fc4_w[j * 97 + k], a4);
            }
            h1 = fmaxf(a1, 0.f) * fc2_w[j];
            h3 = fmaxf(a3, 0.f) * sc_w[j];
            base_l[j] = a4;
            dco_l[j]  = fc4_w[j * 97 + 96];
            f5_l[j]   = fc5_w[j];
        }
        float s1 = h1, s3 = h3;
        #pragma unroll
        for (int off = 32; off > 0; off >>= 1) {
            s1 += __shfl_xor(s1, off, 64);
            s3 += __shfl_xor(s3, off, 64);
        }
        float game = tanhf(s1 + fc2_b[0]);
        float scal = s3 + sc_b[0];
        if (lane == 0) out[b] = game;

        float z = -3.0e38f;
        if (lane < 41) {
            float dval = (float)(lane - 20);
            float lg = fc5_b[0];
            #pragma unroll
            for (int jj = 0; jj < CV; ++jj) {
                float t2 = fmaf(dval, dco_l[jj], base_l[jj]);
                t2 = fmaxf(t2, 0.f);
                lg = fmaf(t2, f5_l[jj], lg);
            }
            z = lg * scal;
        }
        float mz = z;
        #pragma unroll
        for (int off = 32; off > 0; off >>= 1) mz = fmaxf(mz, __shfl_xor(mz, off, 64));
        float e = (lane < 41) ? expf(z - mz) : 0.f;
        float se = e;
        #pragma unroll
        for (int off = 32; off > 0; off >>= 1) se += __shfl_xor(se, off, 64);
        if (lane < 41) out[B + b * 41 + lane] = e / se;
    }
}

extern "C" void kernel_launch(void* const* d_in, const int* in_sizes, int n_in,
                              void* d_out, int out_size, void* d_ws, size_t ws_size,
                              hipStream_t stream) {
    const float* x      = (const float*)d_in[0];
    const float* conv_w = (const float*)d_in[1];
    const float* fc1_w  = (const float*)d_in[2];
    const float* fc1_b  = (const float*)d_in[3];
    const float* fc2_w  = (const float*)d_in[4];
    const float* fc2_b  = (const float*)d_in[5];
    const float* fc3_w  = (const float*)d_in[6];
    const float* fc3_b  = (const float*)d_in[7];
    const float* sc_w   = (const float*)d_in[8];
    const float* sc_b   = (const float*)d_in[9];
    const float* fc4_w  = (const float*)d_in[10];
    const float* fc4_b  = (const float*)d_in[11];
    const float* fc5_w  = (const float*)d_in[12];
    const float* fc5_b  = (const float*)d_in[13];
    float* out = (float*)d_out;

    int B = in_sizes[0] / (C_IN * HW);

    vh_fused<<<dim3(B), dim3(NTHR), 0, stream>>>(
        x, conv_w, fc1_w, fc1_b, fc2_w, fc2_b, fc3_w, fc3_b,
        sc_w, sc_b, fc4_w, fc4_b, fc5_w, fc5_b, out, B);
}